// Round 8
// baseline (51.685 us; speedup 1.0000x reference)
//
#include <hip/hip_runtime.h>

#define NWIN 121
#define NQ 10
#define NGATES 23
#define WPB 4          // waves (samples) per block

typedef float v2f __attribute__((ext_vector_type(2)));

// Pin scheduling at gate granularity: ALU/VALU/SALU may cross (mask 0x7),
// DS/VMEM loads may NOT be hoisted across -> caps register pressure spikes
// (rounds 6/7 spilled ~1MB scratch from ds_read hoisting across 7 gates).
#define SB() __builtin_amdgcn_sched_barrier(0x7)

// type 0 = fused conv block (u3⊗u3 · XX·YY·ZZ · u3⊗u3), type 1 = CRot.
__device__ static const int dGT[NGATES] = {0,0,0,0,0,0,0,0,0, 1,1,1,1,1, 0,0,0,0, 1,1, 0,0, 1};
__device__ static const int dGL[NGATES] = {0,0,0,0,0,0,0,0,0, 0,0,0,0,0, 1,1,1,1, 1,1, 2,2, 2};
__device__ static const int dGP[NGATES] = {0,2,4,6,8,1,3,5,7, 0,1,2,3,4, 0,2,1,3, 0,1, 0,1, 0};

// ---- 4-phase register-resident schedule (g0..g4 absorbed into init) -------
// (schedule + swizzles verified bit-exact in rounds 6/7: absmax = 0)
__host__ __device__ constexpr int REGB[4][4] = {
    {5,6,7,8},{1,2,3,4},{0,1,3,5},{3,5,7,9}};
__host__ __device__ constexpr int LANEB[4][6] = {
    {0,1,2,3,4,9},{0,5,6,7,8,9},{2,4,6,7,8,9},{0,1,2,4,6,8}};

__host__ __device__ constexpr int hswz(int p, int L){
    return p==0 ? ((((L>>5)&1)<<1)|(((L>>6)&1)<<2)|(((L>>7)&1)<<3))
         : p==1 ? (((L>>4)&1) | ((((L>>5)&1)^((L>>6)&1))<<1) | (((L>>7)&1)<<2) | (((L>>8)&1)<<3))
         :        (((L>>4)&1) | (((L>>6)&1)<<1) | (((L>>8)&1)<<3));   // p=2
}
__host__ __device__ constexpr int offsL(int ph, int r){
    int o = 0;
    for (int k=0;k<4;++k) if ((r>>k)&1) o |= 1<<REGB[ph][k];
    return o;
}

struct cpx { float x, y; };
__device__ __forceinline__ cpx cmul(cpx a, cpx b){ return {a.x*b.x - a.y*b.y, a.x*b.y + a.y*b.x}; }
__device__ __forceinline__ cpx cadd(cpx a, cpx b){ return {a.x+b.x, a.y+b.y}; }
__device__ __forceinline__ cpx cscale(float s, cpx a){ return {s*a.x, s*a.y}; }
__device__ __forceinline__ cpx cexp_i(float t){ return {cosf(t), sinf(t)}; }
__device__ __forceinline__ cpx mulnegi(cpx z){ return {z.y, -z.x}; }   // -i*z

__device__ __forceinline__ void u3m(cpx A[2][2], float th, float ph, float de){
    float ct = cosf(0.5f*th), st = sinf(0.5f*th);
    cpx ed  = cexp_i(de);
    cpx ep  = cexp_i(ph);
    cpx epd = cexp_i(ph + de);
    A[0][0] = {ct, 0.f};
    A[0][1] = {-ed.x*st, -ed.y*st};
    A[1][0] = { ep.x*st,  ep.y*st};
    A[1][1] = { epd.x*ct, epd.y*ct};
}

// Build COLUMN c of fused gate g's 4x4 matrix (thread-parallel build: 92 thr).
__device__ __forceinline__ void build_gate_col(int g, int c,
                                               const float* __restrict__ conv,
                                               const float* __restrict__ pool,
                                               cpx (&Mc)[4])
{
    int l = dGL[g], pi = dGP[g];
    if (dGT[g] == 0) {
        const float* W1 = conv + l*150 + pi*15;
        const float* W2 = conv + l*150 + (pi+1)*15;
        cpx A1[2][2], B1[2][2], A2[2][2], B2[2][2];
        u3m(A1, W1[0],  W1[1],  W1[2]);
        u3m(B1, W2[3],  W2[4],  W2[5]);
        u3m(A2, W1[9],  W1[10], W1[11]);
        u3m(B2, W2[12], W2[13], W2[14]);
        const int c1 = c >> 1, c2 = c & 1;
        cpx T[4];
        #pragma unroll
        for (int r1=0;r1<2;++r1)
        #pragma unroll
        for (int r2=0;r2<2;++r2)
            T[2*r1+r2] = cmul(A1[r1][c1], B1[r2][c2]);
        float tz = W1[6];
        cpx em = cexp_i(-0.5f*tz), ep = cexp_i(0.5f*tz);
        T[0] = cmul(em, T[0]); T[1] = cmul(ep, T[1]);
        T[2] = cmul(ep, T[2]); T[3] = cmul(em, T[3]);
        float ty = W1[7]; float cy = cosf(0.5f*ty), sy = sinf(0.5f*ty);
        cpx T2_[4];
        T2_[0] = cadd(cscale(cy,T[0]), mulnegi(cscale(-sy, T[3])));
        T2_[1] = cadd(cscale(cy,T[1]), mulnegi(cscale( sy, T[2])));
        T2_[2] = cadd(cscale(cy,T[2]), mulnegi(cscale( sy, T[1])));
        T2_[3] = cadd(cscale(cy,T[3]), mulnegi(cscale(-sy, T[0])));
        float tx = W1[8]; float cx = cosf(0.5f*tx), sx = sinf(0.5f*tx);
        cpx T3_[4];
        T3_[0] = cadd(cscale(cx,T2_[0]), mulnegi(cscale(sx, T2_[3])));
        T3_[1] = cadd(cscale(cx,T2_[1]), mulnegi(cscale(sx, T2_[2])));
        T3_[2] = cadd(cscale(cx,T2_[2]), mulnegi(cscale(sx, T2_[1])));
        T3_[3] = cadd(cscale(cx,T2_[3]), mulnegi(cscale(sx, T2_[0])));
        cpx K2[4][4];
        #pragma unroll
        for (int r1=0;r1<2;++r1)
        #pragma unroll
        for (int r2=0;r2<2;++r2)
        #pragma unroll
        for (int d1=0;d1<2;++d1)
        #pragma unroll
        for (int d2=0;d2<2;++d2)
            K2[2*r1+r2][2*d1+d2] = cmul(A2[r1][d1], B2[r2][d2]);
        #pragma unroll
        for (int r=0;r<4;++r) {
            cpx acc = {0.f, 0.f};
            #pragma unroll
            for (int m=0;m<4;++m) acc = cadd(acc, cmul(K2[r][m], T3_[m]));
            Mc[r] = acc;
        }
    } else {
        const float* Pp = pool + l*15 + pi*3;
        float phi = Pp[0], th = Pp[1], om = Pp[2];
        float ct = cosf(0.5f*th), st = sinf(0.5f*th);
        #pragma unroll
        for (int r=0;r<4;++r) Mc[r] = {0.f, 0.f};
        if (c == 0) Mc[0] = {1.f, 0.f};
        if (c == 1) Mc[1] = {1.f, 0.f};
        if (c == 2) { Mc[2] = cscale( ct, cexp_i(-0.5f*(phi+om)));
                      Mc[3] = cscale( st, cexp_i(-0.5f*(phi-om))); }
        if (c == 3) { Mc[2] = cscale(-st, cexp_i( 0.5f*(phi-om)));
                      Mc[3] = cscale( ct, cexp_i( 0.5f*(phi+om))); }
    }
}

// ---- sim helpers -----------------------------------------------------------

__device__ __forceinline__ v2f cfma(v2f m, v2f v, v2f acc) {
    v2f sw = {v.y, v.x};
    v2f my = {-m.y, m.y};
    v2f t = __builtin_elementwise_fma(my, sw, acc);
    v2f mx = {m.x, m.x};
    return __builtin_elementwise_fma(mx, v, t);
}
__device__ __forceinline__ v2f cmulv(v2f a, v2f b) { return cfma(a, b, (v2f){0.f,0.f}); }
__device__ __forceinline__ v2f vsel(int c, v2f a, v2f b) {
    return (v2f){ c ? a.x : b.x, c ? a.y : b.y };
}

// wave-local LDS fence: drain this wave's outstanding DS ops; no s_barrier.
__device__ __forceinline__ void wave_lds_fence() {
    asm volatile("s_waitcnt lgkmcnt(0)" ::: "memory");
}

// dense 4x4 gate on register bits P1,P2; matrix loaded from LDS inside.
template<int P1, int P2>
__device__ __forceinline__ void gate4(v2f (&st)[16], const float2* __restrict__ g) {
    v2f m[16];
    const float4* g4 = reinterpret_cast<const float4*>(g);
    #pragma unroll
    for (int k = 0; k < 8; ++k) {
        float4 t = g4[k];
        m[2*k]   = (v2f){t.x, t.y};
        m[2*k+1] = (v2f){t.z, t.w};
    }
    constexpr int M1 = 1 << P1, M2 = 1 << P2;
    #pragma unroll
    for (int b = 0; b < 16; ++b) {
        if (b & (M1 | M2)) continue;
        v2f v0 = st[b], v1 = st[b|M2], v2 = st[b|M1], v3 = st[b|M1|M2];
        #pragma unroll
        for (int row = 0; row < 4; ++row) {
            v2f acc = cfma(m[row*4+0], v0, (v2f){0.f, 0.f});
            acc = cfma(m[row*4+1], v1, acc);
            acc = cfma(m[row*4+2], v2, acc);
            acc = cfma(m[row*4+3], v3, acc);
            st[b | ((row>>1) ? M1 : 0) | ((row&1) ? M2 : 0)] = acc;
        }
    }
}

// CRot on register bits: P1 = ctrl, P2 = tgt. Loads active 2x2 block only.
template<int P1, int P2>
__device__ __forceinline__ void crot4(v2f (&st)[16], const float2* __restrict__ g) {
    const float4* g4 = reinterpret_cast<const float4*>(g);
    float4 a = g4[5], bb = g4[7];
    v2f m22 = {a.x,a.y}, m23 = {a.z,a.w}, m32 = {bb.x,bb.y}, m33 = {bb.z,bb.w};
    constexpr int M1 = 1 << P1, M2 = 1 << P2;
    #pragma unroll
    for (int b = 0; b < 16; ++b) {
        if (!(b & M1) || (b & M2)) continue;
        v2f v2_ = st[b], v3_ = st[b|M2];
        st[b]    = cfma(m23, v3_, cmulv(m22, v2_));
        st[b|M2] = cfma(m33, v3_, cmulv(m32, v2_));
    }
}

// Mixed CRot: ctrl bit at reg pos PCTRL, tgt bit at LANE bit LBIT.
template<int PCTRL, int LBIT>
__device__ __forceinline__ void crotx(v2f (&st)[16], const float2* __restrict__ g, int lane) {
    const float4* g4 = reinterpret_cast<const float4*>(g);
    float4 a = g4[5], bb = g4[7];
    v2f m22 = {a.x,a.y}, m23 = {a.z,a.w}, m32 = {bb.x,bb.y}, m33 = {bb.z,bb.w};
    const int beta = (lane >> LBIT) & 1;
    v2f S0 = vsel(beta, m33, m22);
    v2f S1 = vsel(beta, m32, m23);
    constexpr int M1 = 1 << PCTRL;
    #pragma unroll
    for (int b = 0; b < 16; ++b) {
        if (!(b & M1)) continue;         // ctrl = 1 amps
        v2f u = st[b], p;
        p.x = __shfl_xor(u.x, 1 << LBIT);
        p.y = __shfl_xor(u.y, 1 << LBIT);
        st[b] = cfma(S1, p, cmulv(S0, u));
    }
}

// Mixed dense gate: one bit at reg pos PREG, other at LANE bit LBIT.
template<int PREG, int LBIT>
__device__ __forceinline__ void gate4x(v2f (&st)[16], const float2* __restrict__ g, int lane) {
    v2f m[16];
    const float4* g4 = reinterpret_cast<const float4*>(g);
    #pragma unroll
    for (int k = 0; k < 8; ++k) {
        float4 t = g4[k];
        m[2*k]   = (v2f){t.x, t.y};
        m[2*k+1] = (v2f){t.z, t.w};
    }
    const int beta = (lane >> LBIT) & 1;
    v2f A00 = vsel(beta, m[5],  m[0]);
    v2f A01 = vsel(beta, m[4],  m[1]);
    v2f A02 = vsel(beta, m[7],  m[2]);
    v2f A03 = vsel(beta, m[6],  m[3]);
    v2f A10 = vsel(beta, m[13], m[8]);
    v2f A11 = vsel(beta, m[12], m[9]);
    v2f A12 = vsel(beta, m[15], m[10]);
    v2f A13 = vsel(beta, m[14], m[11]);
    constexpr int M1 = 1 << PREG;
    #pragma unroll
    for (int b = 0; b < 16; ++b) {
        if (b & M1) continue;
        v2f u0 = st[b], u1 = st[b|M1], p0, p1;
        p0.x = __shfl_xor(u0.x, 1 << LBIT); p0.y = __shfl_xor(u0.y, 1 << LBIT);
        p1.x = __shfl_xor(u1.x, 1 << LBIT); p1.y = __shfl_xor(u1.y, 1 << LBIT);
        v2f r0 = cfma(A03, p1, cfma(A02, u1, cfma(A01, p0, cmulv(A00, u0))));
        v2f r1 = cfma(A13, p1, cfma(A12, u1, cfma(A11, p0, cmulv(A10, u0))));
        st[b] = r0; st[b|M1] = r1;
    }
}

template<int PH>
__device__ __forceinline__ int base_of(int lane) {
    int b = 0;
    #pragma unroll
    for (int j = 0; j < 6; ++j) b |= ((lane >> j) & 1) << LANEB[PH][j];
    return b;
}

// LDS re-permute (double-buffered, wave-local) from phase P to phase P+1.
template<int P>
__device__ __forceinline__ void permute(v2f (&st)[16], char* buf, int lane) {
    int bw0 = base_of<P>(lane);
    int bw = (bw0 ^ hswz(P, bw0)) << 3;
    #pragma unroll
    for (int r = 0; r < 16; ++r) {
        const int o = offsL(P, r);
        const int C = (o ^ hswz(P, o)) << 3;
        *reinterpret_cast<v2f*>(buf + (bw ^ C)) = st[r];
    }
    wave_lds_fence();
    int br0 = base_of<P+1>(lane);
    int br = (br0 ^ hswz(P, br0)) << 3;
    #pragma unroll
    for (int r = 0; r < 16; ++r) {
        const int o = offsL(P+1, r);
        const int C = (o ^ hswz(P, o)) << 3;
        st[r] = *reinterpret_cast<const v2f*>(buf + (br ^ C));
    }
}

// Single fused kernel. Block = 256 threads = 4 waves = 4 samples.
__global__ __launch_bounds__(256, 2) void hqtcn_fused(
    const float* __restrict__ x,      // (16, 32, 128)
    const float* __restrict__ fc_w,   // (10, 256)
    const float* __restrict__ fc_b,   // (10,)
    const float* __restrict__ conv,   // (3, 10, 15)
    const float* __restrict__ pool,   // (3, 5, 3)
    float* __restrict__ out)          // (1936,)
{
    __shared__ float2 gmat[NGATES*16];        // 2944 B gate matrices
    __shared__ float2 pbuf[WPB][2][1024];     // 2 x 8 KB per-wave permute bufs

    const int tid  = threadIdx.x;
    const int wid  = tid >> 6;
    const int lane = tid & 63;
    const int s = blockIdx.x * WPB + wid;     // 484*4 = 1936 exact
    const int b = s / NWIN, w = s % NWIN;

    // ---- issue x loads early
    float xv[4];
    #pragma unroll
    for (int j = 0; j < 4; ++j) {
        int f = lane + 64*j;
        xv[j] = x[b*4096 + (f >> 3)*128 + w + (f & 7)];
    }

    // ---- parallel gate build: thread (g, c) computes column c of gate g
    if (tid < 4*NGATES) {
        cpx Mc[4];
        build_gate_col(tid >> 2, tid & 3, conv, pool, Mc);
        #pragma unroll
        for (int r = 0; r < 4; ++r)
            gmat[(tid>>2)*16 + r*4 + (tid&3)] = make_float2(Mc[r].x, Mc[r].y);
    }

    // ---- angles (per wave)
    float cq[NQ], sq[NQ];
    #pragma unroll
    for (int e = 0; e < NQ; ++e) {
        float v = 0.f;
        #pragma unroll
        for (int j = 0; j < 4; ++j)
            v = fmaf(xv[j], fc_w[e*256 + lane + 64*j], v);
        #pragma unroll
        for (int off = 32; off >= 1; off >>= 1) v += __shfl_xor(v, off);
        float h = 0.5f * (v + fc_b[e]);
        __sincosf(h, &sq[e], &cq[e]);
    }
    __syncthreads();    // the only block-wide barrier (gmat ready)
    SB();

    // ---- init: apply g0..g4 analytically. W[p] = G_p @ [cc',cs',sc',ss']
    v2f W[5][4];
    #pragma unroll
    for (int p = 0; p < 5; ++p) {
        float ca = cq[2*p], sa = sq[2*p], cb = cq[2*p+1], sb = sq[2*p+1];
        float u0 = ca*cb, u1 = ca*sb, u2 = sa*cb, u3_ = sa*sb;
        const float2* G = gmat + p*16;
        #pragma unroll
        for (int i = 0; i < 4; ++i) {
            float2 g0 = G[i*4+0], g1 = G[i*4+1], g2 = G[i*4+2], g3 = G[i*4+3];
            v2f acc = (v2f){g0.x*u0, g0.y*u0};
            acc = __builtin_elementwise_fma((v2f){u1,u1}, (v2f){g1.x,g1.y}, acc);
            acc = __builtin_elementwise_fma((v2f){u2,u2}, (v2f){g2.x,g2.y}, acc);
            acc = __builtin_elementwise_fma((v2f){u3_,u3_}, (v2f){g3.x,g3.y}, acc);
            W[p][i] = acc;
        }
    }
    // Phase-A mapping: reg bits = logical {5,6,7,8}; lane bits = {0,1,2,3,4,9}
    const int l0 = lane&1, l1=(lane>>1)&1, l2=(lane>>2)&1,
              l3=(lane>>3)&1, l4=(lane>>4)&1, l5=(lane>>5)&1;
    v2f W3k = vsel(l3, vsel(l2, W[3][3], W[3][2]), vsel(l2, W[3][1], W[3][0]));
    v2f W4k = vsel(l1, vsel(l0, W[4][3], W[4][2]), vsel(l0, W[4][1], W[4][0]));
    v2f UL  = cmulv(W3k, W4k);
    v2f W2lo = vsel(l4, W[2][1], W[2][0]);
    v2f W2hi = vsel(l4, W[2][3], W[2][2]);
    v2f P0v = cmulv(UL, vsel(l5, W[0][2], W[0][0]));
    v2f P1v = cmulv(UL, vsel(l5, W[0][3], W[0][1]));
    v2f PW[2][4];
    #pragma unroll
    for (int j = 0; j < 4; ++j) {
        PW[0][j] = cmulv(P0v, W[1][j]);
        PW[1][j] = cmulv(P1v, W[1][j]);
    }
    v2f st[16];
    #pragma unroll
    for (int r = 0; r < 16; ++r)
        st[r] = cmulv(PW[(r>>3)&1][(r>>1)&3], (r&1) ? W2hi : W2lo);
    SB();

    const float2* gm = gmat;

    // Phase A: reg {5,6,7,8}, lane {0,1,2,3,4,9}
    gate4<3,2>(st, gm + 5*16);          SB();  // g5  {8,7}
    gate4<1,0>(st, gm + 6*16);          SB();  // g6  {6,5}
    crot4<1,2>(st, gm + 10*16);         SB();  // g10 ctrl6->7
    crotx<3,5>(st, gm + 9*16, lane);    SB();  // g9  ctrl8(reg3)->9(lane5)
    permute<0>(st, (char*)&pbuf[wid][0][0], lane);
    SB();
    // Phase B: reg {1,2,3,4}, lane {0,5,6,7,8,9}
    gate4<3,2>(st, gm + 7*16);          SB();  // g7  {4,3}
    gate4<1,0>(st, gm + 8*16);          SB();  // g8  {2,1}
    crot4<1,2>(st, gm + 12*16);         SB();  // g12 ctrl2->3
    crotx<3,1>(st, gm + 11*16, lane);   SB();  // g11 ctrl4(reg3)->5(lane1)
    permute<1>(st, (char*)&pbuf[wid][1][0], lane);
    SB();
    // Phase D: reg {0,1,3,5}, lane {2,4,6,7,8,9}
    crot4<0,1>(st, gm + 13*16);         SB();  // g13 ctrl0->1
    gate4<3,2>(st, gm + 15*16);         SB();  // g15 {5,3}
    gate4<2,1>(st, gm + 17*16);         SB();  // g17 {3,1}
    permute<2>(st, (char*)&pbuf[wid][0][0], lane);
    SB();
    // Phase E: reg {3,5,7,9}, lane {0,1,2,4,6,8}
    gate4<3,2>(st, gm + 14*16);         SB();  // g14 {9,7}
    gate4<2,1>(st, gm + 16*16);         SB();  // g16 {7,5}
    crot4<2,3>(st, gm + 18*16);         SB();  // g18 ctrl7->9
    crot4<0,1>(st, gm + 19*16);         SB();  // g19 ctrl3->5
    gate4<3,1>(st, gm + 20*16);         SB();  // g20 {9,5}
    gate4x<1,1>(st, gm + 21*16, lane);  SB();  // g21 {5(reg1), 1(lane1)}
    crot4<1,3>(st, gm + 22*16);         SB();  // g22 ctrl5->9

    // ---- <Z0>: logical bit 9 at reg pos 3 in phase E.
    float accp = 0.f, accm = 0.f;
    #pragma unroll
    for (int r = 0; r < 16; ++r) {
        v2f a = st[r];
        float p2 = fmaf(a.x, a.x, a.y*a.y);
        if ((r >> 3) & 1) accm += p2; else accp += p2;
    }
    float acc = accp - accm;
    #pragma unroll
    for (int off = 32; off >= 1; off >>= 1) acc += __shfl_xor(acc, off);
    if (lane == 0) out[s] = acc;
}

extern "C" void kernel_launch(void* const* d_in, const int* in_sizes, int n_in,
                              void* d_out, int out_size, void* d_ws, size_t ws_size,
                              hipStream_t stream) {
    const float* x     = (const float*)d_in[0];
    const float* fc_w  = (const float*)d_in[1];
    const float* fc_b  = (const float*)d_in[2];
    const float* convp = (const float*)d_in[3];
    const float* poolp = (const float*)d_in[4];
    float* out = (float*)d_out;

    hqtcn_fused<<<(16*NWIN)/WPB, 64*WPB, 0, stream>>>(x, fc_w, fc_b, convp, poolp, out);
}

// Round 9
// 24.914 us; speedup vs baseline: 2.0745x; 2.0745x over previous
//
#include <hip/hip_runtime.h>

#define NWIN 121
#define NQ 10
#define NGATES 23
#define WPB 4          // waves (samples) per block

typedef float v2f __attribute__((ext_vector_type(2)));

// Pin scheduling at gate granularity: ALU/VALU/SALU may cross (mask 0x7),
// DS/VMEM loads may NOT be hoisted across.
#define SB() __builtin_amdgcn_sched_barrier(0x7)

// type 0 = fused conv block (u3⊗u3 · XX·YY·ZZ · u3⊗u3), type 1 = CRot.
__device__ static const int dGT[NGATES] = {0,0,0,0,0,0,0,0,0, 1,1,1,1,1, 0,0,0,0, 1,1, 0,0, 1};
__device__ static const int dGL[NGATES] = {0,0,0,0,0,0,0,0,0, 0,0,0,0,0, 1,1,1,1, 1,1, 2,2, 2};
__device__ static const int dGP[NGATES] = {0,2,4,6,8,1,3,5,7, 0,1,2,3,4, 0,2,1,3, 0,1, 0,1, 0};

// ---- 4-phase register-resident schedule (g0..g4 absorbed into init) -------
// (schedule + swizzles verified bit-exact in rounds 6-8: absmax = 0)
__host__ __device__ constexpr int REGB[4][4] = {
    {5,6,7,8},{1,2,3,4},{0,1,3,5},{3,5,7,9}};
__host__ __device__ constexpr int LANEB[4][6] = {
    {0,1,2,3,4,9},{0,5,6,7,8,9},{2,4,6,7,8,9},{0,1,2,4,6,8}};

__host__ __device__ constexpr int hswz(int p, int L){
    return p==0 ? ((((L>>5)&1)<<1)|(((L>>6)&1)<<2)|(((L>>7)&1)<<3))
         : p==1 ? (((L>>4)&1) | ((((L>>5)&1)^((L>>6)&1))<<1) | (((L>>7)&1)<<2) | (((L>>8)&1)<<3))
         :        (((L>>4)&1) | (((L>>6)&1)<<1) | (((L>>8)&1)<<3));   // p=2
}
__host__ __device__ constexpr int offsL(int ph, int r){
    int o = 0;
    for (int k=0;k<4;++k) if ((r>>k)&1) o |= 1<<REGB[ph][k];
    return o;
}

struct cpx { float x, y; };
__device__ __forceinline__ cpx cmul(cpx a, cpx b){ return {a.x*b.x - a.y*b.y, a.x*b.y + a.y*b.x}; }
__device__ __forceinline__ cpx cadd(cpx a, cpx b){ return {a.x+b.x, a.y+b.y}; }
__device__ __forceinline__ cpx cscale(float s, cpx a){ return {s*a.x, s*a.y}; }
__device__ __forceinline__ cpx cexp_i(float t){ return {cosf(t), sinf(t)}; }
__device__ __forceinline__ cpx mulnegi(cpx z){ return {z.y, -z.x}; }   // -i*z
// runtime-condition select with STATIC indices only (v_cndmask, no scratch)
__device__ __forceinline__ cpx csel(int c, cpx a, cpx b){ return {c ? a.x : b.x, c ? a.y : b.y}; }

__device__ __forceinline__ void u3m(cpx A[2][2], float th, float ph, float de){
    float ct = cosf(0.5f*th), st = sinf(0.5f*th);
    cpx ed  = cexp_i(de);
    cpx ep  = cexp_i(ph);
    cpx epd = cexp_i(ph + de);
    A[0][0] = {ct, 0.f};
    A[0][1] = {-ed.x*st, -ed.y*st};
    A[1][0] = { ep.x*st,  ep.y*st};
    A[1][1] = { epd.x*ct, epd.y*ct};
}

// Build COLUMN c of fused gate g's 4x4 matrix. ALL array indices static;
// the runtime column choice happens via csel (cndmask). Rule-#20 safe:
// rounds 6-8 used A1[r1][c1] with runtime c1 -> ~920KB scratch per dispatch.
__device__ __forceinline__ void build_gate_col(int g, int c,
                                               const float* __restrict__ conv,
                                               const float* __restrict__ pool,
                                               cpx (&Mc)[4])
{
    int l = dGL[g], pi = dGP[g];
    if (dGT[g] == 0) {
        const float* W1 = conv + l*150 + pi*15;
        const float* W2 = conv + l*150 + (pi+1)*15;
        cpx A1[2][2], B1[2][2], A2[2][2], B2[2][2];
        u3m(A1, W1[0],  W1[1],  W1[2]);
        u3m(B1, W2[3],  W2[4],  W2[5]);
        u3m(A2, W1[9],  W1[10], W1[11]);
        u3m(B2, W2[12], W2[13], W2[14]);
        const int c1 = c >> 1, c2 = c & 1;
        // column c1 of A1, column c2 of B1 — static indices + cndmask select
        cpx a1r0 = csel(c1, A1[0][1], A1[0][0]);
        cpx a1r1 = csel(c1, A1[1][1], A1[1][0]);
        cpx b1r0 = csel(c2, B1[0][1], B1[0][0]);
        cpx b1r1 = csel(c2, B1[1][1], B1[1][0]);
        cpx T[4];                     // T[2*r1+r2] = A1[r1][c1] * B1[r2][c2]
        T[0] = cmul(a1r0, b1r0);
        T[1] = cmul(a1r0, b1r1);
        T[2] = cmul(a1r1, b1r0);
        T[3] = cmul(a1r1, b1r1);
        float tz = W1[6];
        cpx em = cexp_i(-0.5f*tz), ep = cexp_i(0.5f*tz);
        T[0] = cmul(em, T[0]); T[1] = cmul(ep, T[1]);
        T[2] = cmul(ep, T[2]); T[3] = cmul(em, T[3]);
        float ty = W1[7]; float cy = cosf(0.5f*ty), sy = sinf(0.5f*ty);
        cpx T2_[4];
        T2_[0] = cadd(cscale(cy,T[0]), mulnegi(cscale(-sy, T[3])));
        T2_[1] = cadd(cscale(cy,T[1]), mulnegi(cscale( sy, T[2])));
        T2_[2] = cadd(cscale(cy,T[2]), mulnegi(cscale( sy, T[1])));
        T2_[3] = cadd(cscale(cy,T[3]), mulnegi(cscale(-sy, T[0])));
        float tx = W1[8]; float cx = cosf(0.5f*tx), sx = sinf(0.5f*tx);
        cpx T3_[4];
        T3_[0] = cadd(cscale(cx,T2_[0]), mulnegi(cscale(sx, T2_[3])));
        T3_[1] = cadd(cscale(cx,T2_[1]), mulnegi(cscale(sx, T2_[2])));
        T3_[2] = cadd(cscale(cx,T2_[2]), mulnegi(cscale(sx, T2_[1])));
        T3_[3] = cadd(cscale(cx,T2_[3]), mulnegi(cscale(sx, T2_[0])));
        cpx K2[4][4];
        #pragma unroll
        for (int r1=0;r1<2;++r1)
        #pragma unroll
        for (int r2=0;r2<2;++r2)
        #pragma unroll
        for (int d1=0;d1<2;++d1)
        #pragma unroll
        for (int d2=0;d2<2;++d2)
            K2[2*r1+r2][2*d1+d2] = cmul(A2[r1][d1], B2[r2][d2]);
        #pragma unroll
        for (int r=0;r<4;++r) {
            cpx acc = {0.f, 0.f};
            #pragma unroll
            for (int m=0;m<4;++m) acc = cadd(acc, cmul(K2[r][m], T3_[m]));
            Mc[r] = acc;
        }
    } else {
        const float* Pp = pool + l*15 + pi*3;
        float phi = Pp[0], th = Pp[1], om = Pp[2];
        float ct = cosf(0.5f*th), st = sinf(0.5f*th);
        cpx z = {0.f, 0.f}, one = {1.f, 0.f};
        cpx m22 = cscale( ct, cexp_i(-0.5f*(phi+om)));
        cpx m32 = cscale( st, cexp_i(-0.5f*(phi-om)));
        cpx m23 = cscale(-st, cexp_i( 0.5f*(phi-om)));
        cpx m33 = cscale( ct, cexp_i( 0.5f*(phi+om)));
        // column c of the CRot matrix, all static stores + cndmask
        Mc[0] = csel(c == 0, one, z);
        Mc[1] = csel(c == 1, one, z);
        Mc[2] = csel(c == 2, m22, csel(c == 3, m23, z));
        Mc[3] = csel(c == 2, m32, csel(c == 3, m33, z));
    }
}

// ---- sim helpers -----------------------------------------------------------

__device__ __forceinline__ v2f cfma(v2f m, v2f v, v2f acc) {
    v2f sw = {v.y, v.x};
    v2f my = {-m.y, m.y};
    v2f t = __builtin_elementwise_fma(my, sw, acc);
    v2f mx = {m.x, m.x};
    return __builtin_elementwise_fma(mx, v, t);
}
__device__ __forceinline__ v2f cmulv(v2f a, v2f b) { return cfma(a, b, (v2f){0.f,0.f}); }
__device__ __forceinline__ v2f vsel(int c, v2f a, v2f b) {
    return (v2f){ c ? a.x : b.x, c ? a.y : b.y };
}

// wave-local LDS fence: drain this wave's outstanding DS ops; no s_barrier.
__device__ __forceinline__ void wave_lds_fence() {
    asm volatile("s_waitcnt lgkmcnt(0)" ::: "memory");
}

// dense 4x4 gate on register bits P1,P2; matrix loaded from LDS inside.
template<int P1, int P2>
__device__ __forceinline__ void gate4(v2f (&st)[16], const float2* __restrict__ g) {
    v2f m[16];
    const float4* g4 = reinterpret_cast<const float4*>(g);
    #pragma unroll
    for (int k = 0; k < 8; ++k) {
        float4 t = g4[k];
        m[2*k]   = (v2f){t.x, t.y};
        m[2*k+1] = (v2f){t.z, t.w};
    }
    constexpr int M1 = 1 << P1, M2 = 1 << P2;
    #pragma unroll
    for (int b = 0; b < 16; ++b) {
        if (b & (M1 | M2)) continue;
        v2f v0 = st[b], v1 = st[b|M2], v2 = st[b|M1], v3 = st[b|M1|M2];
        #pragma unroll
        for (int row = 0; row < 4; ++row) {
            v2f acc = cfma(m[row*4+0], v0, (v2f){0.f, 0.f});
            acc = cfma(m[row*4+1], v1, acc);
            acc = cfma(m[row*4+2], v2, acc);
            acc = cfma(m[row*4+3], v3, acc);
            st[b | ((row>>1) ? M1 : 0) | ((row&1) ? M2 : 0)] = acc;
        }
    }
}

// CRot on register bits: P1 = ctrl, P2 = tgt. Loads active 2x2 block only.
template<int P1, int P2>
__device__ __forceinline__ void crot4(v2f (&st)[16], const float2* __restrict__ g) {
    const float4* g4 = reinterpret_cast<const float4*>(g);
    float4 a = g4[5], bb = g4[7];
    v2f m22 = {a.x,a.y}, m23 = {a.z,a.w}, m32 = {bb.x,bb.y}, m33 = {bb.z,bb.w};
    constexpr int M1 = 1 << P1, M2 = 1 << P2;
    #pragma unroll
    for (int b = 0; b < 16; ++b) {
        if (!(b & M1) || (b & M2)) continue;
        v2f v2_ = st[b], v3_ = st[b|M2];
        st[b]    = cfma(m23, v3_, cmulv(m22, v2_));
        st[b|M2] = cfma(m33, v3_, cmulv(m32, v2_));
    }
}

// Mixed CRot: ctrl bit at reg pos PCTRL, tgt bit at LANE bit LBIT.
template<int PCTRL, int LBIT>
__device__ __forceinline__ void crotx(v2f (&st)[16], const float2* __restrict__ g, int lane) {
    const float4* g4 = reinterpret_cast<const float4*>(g);
    float4 a = g4[5], bb = g4[7];
    v2f m22 = {a.x,a.y}, m23 = {a.z,a.w}, m32 = {bb.x,bb.y}, m33 = {bb.z,bb.w};
    const int beta = (lane >> LBIT) & 1;
    v2f S0 = vsel(beta, m33, m22);
    v2f S1 = vsel(beta, m32, m23);
    constexpr int M1 = 1 << PCTRL;
    #pragma unroll
    for (int b = 0; b < 16; ++b) {
        if (!(b & M1)) continue;         // ctrl = 1 amps
        v2f u = st[b], p;
        p.x = __shfl_xor(u.x, 1 << LBIT);
        p.y = __shfl_xor(u.y, 1 << LBIT);
        st[b] = cfma(S1, p, cmulv(S0, u));
    }
}

// Mixed dense gate: one bit at reg pos PREG, other at LANE bit LBIT.
template<int PREG, int LBIT>
__device__ __forceinline__ void gate4x(v2f (&st)[16], const float2* __restrict__ g, int lane) {
    v2f m[16];
    const float4* g4 = reinterpret_cast<const float4*>(g);
    #pragma unroll
    for (int k = 0; k < 8; ++k) {
        float4 t = g4[k];
        m[2*k]   = (v2f){t.x, t.y};
        m[2*k+1] = (v2f){t.z, t.w};
    }
    const int beta = (lane >> LBIT) & 1;
    v2f A00 = vsel(beta, m[5],  m[0]);
    v2f A01 = vsel(beta, m[4],  m[1]);
    v2f A02 = vsel(beta, m[7],  m[2]);
    v2f A03 = vsel(beta, m[6],  m[3]);
    v2f A10 = vsel(beta, m[13], m[8]);
    v2f A11 = vsel(beta, m[12], m[9]);
    v2f A12 = vsel(beta, m[15], m[10]);
    v2f A13 = vsel(beta, m[14], m[11]);
    constexpr int M1 = 1 << PREG;
    #pragma unroll
    for (int b = 0; b < 16; ++b) {
        if (b & M1) continue;
        v2f u0 = st[b], u1 = st[b|M1], p0, p1;
        p0.x = __shfl_xor(u0.x, 1 << LBIT); p0.y = __shfl_xor(u0.y, 1 << LBIT);
        p1.x = __shfl_xor(u1.x, 1 << LBIT); p1.y = __shfl_xor(u1.y, 1 << LBIT);
        v2f r0 = cfma(A03, p1, cfma(A02, u1, cfma(A01, p0, cmulv(A00, u0))));
        v2f r1 = cfma(A13, p1, cfma(A12, u1, cfma(A11, p0, cmulv(A10, u0))));
        st[b] = r0; st[b|M1] = r1;
    }
}

template<int PH>
__device__ __forceinline__ int base_of(int lane) {
    int b = 0;
    #pragma unroll
    for (int j = 0; j < 6; ++j) b |= ((lane >> j) & 1) << LANEB[PH][j];
    return b;
}

// LDS re-permute (double-buffered, wave-local) from phase P to phase P+1.
template<int P>
__device__ __forceinline__ void permute(v2f (&st)[16], char* buf, int lane) {
    int bw0 = base_of<P>(lane);
    int bw = (bw0 ^ hswz(P, bw0)) << 3;
    #pragma unroll
    for (int r = 0; r < 16; ++r) {
        const int o = offsL(P, r);
        const int C = (o ^ hswz(P, o)) << 3;
        *reinterpret_cast<v2f*>(buf + (bw ^ C)) = st[r];
    }
    wave_lds_fence();
    int br0 = base_of<P+1>(lane);
    int br = (br0 ^ hswz(P, br0)) << 3;
    #pragma unroll
    for (int r = 0; r < 16; ++r) {
        const int o = offsL(P+1, r);
        const int C = (o ^ hswz(P, o)) << 3;
        st[r] = *reinterpret_cast<const v2f*>(buf + (br ^ C));
    }
}

// Single fused kernel. Block = 256 threads = 4 waves = 4 samples.
__global__ __launch_bounds__(256, 2) void hqtcn_fused(
    const float* __restrict__ x,      // (16, 32, 128)
    const float* __restrict__ fc_w,   // (10, 256)
    const float* __restrict__ fc_b,   // (10,)
    const float* __restrict__ conv,   // (3, 10, 15)
    const float* __restrict__ pool,   // (3, 5, 3)
    float* __restrict__ out)          // (1936,)
{
    __shared__ float2 gmat[NGATES*16];        // 2944 B gate matrices
    __shared__ float2 pbuf[WPB][2][1024];     // 2 x 8 KB per-wave permute bufs

    const int tid  = threadIdx.x;
    const int wid  = tid >> 6;
    const int lane = tid & 63;
    const int s = blockIdx.x * WPB + wid;     // 484*4 = 1936 exact
    const int b = s / NWIN, w = s % NWIN;

    // ---- issue x loads early
    float xv[4];
    #pragma unroll
    for (int j = 0; j < 4; ++j) {
        int f = lane + 64*j;
        xv[j] = x[b*4096 + (f >> 3)*128 + w + (f & 7)];
    }

    // ---- parallel gate build: thread (g, c) computes column c of gate g
    if (tid < 4*NGATES) {
        cpx Mc[4];
        build_gate_col(tid >> 2, tid & 3, conv, pool, Mc);
        #pragma unroll
        for (int r = 0; r < 4; ++r)
            gmat[(tid>>2)*16 + r*4 + (tid&3)] = make_float2(Mc[r].x, Mc[r].y);
    }

    // ---- angles (per wave)
    float cq[NQ], sq[NQ];
    #pragma unroll
    for (int e = 0; e < NQ; ++e) {
        float v = 0.f;
        #pragma unroll
        for (int j = 0; j < 4; ++j)
            v = fmaf(xv[j], fc_w[e*256 + lane + 64*j], v);
        #pragma unroll
        for (int off = 32; off >= 1; off >>= 1) v += __shfl_xor(v, off);
        float h = 0.5f * (v + fc_b[e]);
        __sincosf(h, &sq[e], &cq[e]);
    }
    __syncthreads();    // the only block-wide barrier (gmat ready)
    SB();

    // ---- init: apply g0..g4 analytically. W[p] = G_p @ [cc',cs',sc',ss']
    v2f W[5][4];
    #pragma unroll
    for (int p = 0; p < 5; ++p) {
        float ca = cq[2*p], sa = sq[2*p], cb = cq[2*p+1], sb = sq[2*p+1];
        float u0 = ca*cb, u1 = ca*sb, u2 = sa*cb, u3_ = sa*sb;
        const float2* G = gmat + p*16;
        #pragma unroll
        for (int i = 0; i < 4; ++i) {
            float2 g0 = G[i*4+0], g1 = G[i*4+1], g2 = G[i*4+2], g3 = G[i*4+3];
            v2f acc = (v2f){g0.x*u0, g0.y*u0};
            acc = __builtin_elementwise_fma((v2f){u1,u1}, (v2f){g1.x,g1.y}, acc);
            acc = __builtin_elementwise_fma((v2f){u2,u2}, (v2f){g2.x,g2.y}, acc);
            acc = __builtin_elementwise_fma((v2f){u3_,u3_}, (v2f){g3.x,g3.y}, acc);
            W[p][i] = acc;
        }
    }
    // Phase-A mapping: reg bits = logical {5,6,7,8}; lane bits = {0,1,2,3,4,9}
    const int l0 = lane&1, l1=(lane>>1)&1, l2=(lane>>2)&1,
              l3=(lane>>3)&1, l4=(lane>>4)&1, l5=(lane>>5)&1;
    v2f W3k = vsel(l3, vsel(l2, W[3][3], W[3][2]), vsel(l2, W[3][1], W[3][0]));
    v2f W4k = vsel(l1, vsel(l0, W[4][3], W[4][2]), vsel(l0, W[4][1], W[4][0]));
    v2f UL  = cmulv(W3k, W4k);
    v2f W2lo = vsel(l4, W[2][1], W[2][0]);
    v2f W2hi = vsel(l4, W[2][3], W[2][2]);
    v2f P0v = cmulv(UL, vsel(l5, W[0][2], W[0][0]));
    v2f P1v = cmulv(UL, vsel(l5, W[0][3], W[0][1]));
    v2f PW[2][4];
    #pragma unroll
    for (int j = 0; j < 4; ++j) {
        PW[0][j] = cmulv(P0v, W[1][j]);
        PW[1][j] = cmulv(P1v, W[1][j]);
    }
    v2f st[16];
    #pragma unroll
    for (int r = 0; r < 16; ++r)
        st[r] = cmulv(PW[(r>>3)&1][(r>>1)&3], (r&1) ? W2hi : W2lo);
    SB();

    const float2* gm = gmat;

    // Phase A: reg {5,6,7,8}, lane {0,1,2,3,4,9}
    gate4<3,2>(st, gm + 5*16);          SB();  // g5  {8,7}
    gate4<1,0>(st, gm + 6*16);          SB();  // g6  {6,5}
    crot4<1,2>(st, gm + 10*16);         SB();  // g10 ctrl6->7
    crotx<3,5>(st, gm + 9*16, lane);    SB();  // g9  ctrl8(reg3)->9(lane5)
    permute<0>(st, (char*)&pbuf[wid][0][0], lane);
    SB();
    // Phase B: reg {1,2,3,4}, lane {0,5,6,7,8,9}
    gate4<3,2>(st, gm + 7*16);          SB();  // g7  {4,3}
    gate4<1,0>(st, gm + 8*16);          SB();  // g8  {2,1}
    crot4<1,2>(st, gm + 12*16);         SB();  // g12 ctrl2->3
    crotx<3,1>(st, gm + 11*16, lane);   SB();  // g11 ctrl4(reg3)->5(lane1)
    permute<1>(st, (char*)&pbuf[wid][1][0], lane);
    SB();
    // Phase D: reg {0,1,3,5}, lane {2,4,6,7,8,9}
    crot4<0,1>(st, gm + 13*16);         SB();  // g13 ctrl0->1
    gate4<3,2>(st, gm + 15*16);         SB();  // g15 {5,3}
    gate4<2,1>(st, gm + 17*16);         SB();  // g17 {3,1}
    permute<2>(st, (char*)&pbuf[wid][0][0], lane);
    SB();
    // Phase E: reg {3,5,7,9}, lane {0,1,2,4,6,8}
    gate4<3,2>(st, gm + 14*16);         SB();  // g14 {9,7}
    gate4<2,1>(st, gm + 16*16);         SB();  // g16 {7,5}
    crot4<2,3>(st, gm + 18*16);         SB();  // g18 ctrl7->9
    crot4<0,1>(st, gm + 19*16);         SB();  // g19 ctrl3->5
    gate4<3,1>(st, gm + 20*16);         SB();  // g20 {9,5}
    gate4x<1,1>(st, gm + 21*16, lane);  SB();  // g21 {5(reg1), 1(lane1)}
    crot4<1,3>(st, gm + 22*16);         SB();  // g22 ctrl5->9

    // ---- <Z0>: logical bit 9 at reg pos 3 in phase E.
    float accp = 0.f, accm = 0.f;
    #pragma unroll
    for (int r = 0; r < 16; ++r) {
        v2f a = st[r];
        float p2 = fmaf(a.x, a.x, a.y*a.y);
        if ((r >> 3) & 1) accm += p2; else accp += p2;
    }
    float acc = accp - accm;
    #pragma unroll
    for (int off = 32; off >= 1; off >>= 1) acc += __shfl_xor(acc, off);
    if (lane == 0) out[s] = acc;
}

extern "C" void kernel_launch(void* const* d_in, const int* in_sizes, int n_in,
                              void* d_out, int out_size, void* d_ws, size_t ws_size,
                              hipStream_t stream) {
    const float* x     = (const float*)d_in[0];
    const float* fc_w  = (const float*)d_in[1];
    const float* fc_b  = (const float*)d_in[2];
    const float* convp = (const float*)d_in[3];
    const float* poolp = (const float*)d_in[4];
    float* out = (float*)d_out;

    hqtcn_fused<<<(16*NWIN)/WPB, 64*WPB, 0, stream>>>(x, fc_w, fc_b, convp, poolp, out);
}

// Round 10
// 24.744 us; speedup vs baseline: 2.0888x; 1.0069x over previous
//
#include <hip/hip_runtime.h>

#define NWIN 121
#define NQ 10
#define NGATES 23
#define WPB 4          // waves (samples) per block

typedef float v2f __attribute__((ext_vector_type(2)));

// type 0 = fused conv block (u3⊗u3 · XX·YY·ZZ · u3⊗u3), type 1 = CRot.
__device__ static const int dGT[NGATES] = {0,0,0,0,0,0,0,0,0, 1,1,1,1,1, 0,0,0,0, 1,1, 0,0, 1};
__device__ static const int dGL[NGATES] = {0,0,0,0,0,0,0,0,0, 0,0,0,0,0, 1,1,1,1, 1,1, 2,2, 2};
__device__ static const int dGP[NGATES] = {0,2,4,6,8,1,3,5,7, 0,1,2,3,4, 0,2,1,3, 0,1, 0,1, 0};

// ---- 4-phase register-resident schedule (g0..g4 absorbed into init) -------
// (schedule + swizzles verified bit-exact in rounds 6-9: absmax = 0)
__host__ __device__ constexpr int REGB[4][4] = {
    {5,6,7,8},{1,2,3,4},{0,1,3,5},{3,5,7,9}};
__host__ __device__ constexpr int LANEB[4][6] = {
    {0,1,2,3,4,9},{0,5,6,7,8,9},{2,4,6,7,8,9},{0,1,2,4,6,8}};

__host__ __device__ constexpr int hswz(int p, int L){
    return p==0 ? ((((L>>5)&1)<<1)|(((L>>6)&1)<<2)|(((L>>7)&1)<<3))
         : p==1 ? (((L>>4)&1) | ((((L>>5)&1)^((L>>6)&1))<<1) | (((L>>7)&1)<<2) | (((L>>8)&1)<<3))
         :        (((L>>4)&1) | (((L>>6)&1)<<1) | (((L>>8)&1)<<3));   // p=2
}
__host__ __device__ constexpr int offsL(int ph, int r){
    int o = 0;
    for (int k=0;k<4;++k) if ((r>>k)&1) o |= 1<<REGB[ph][k];
    return o;
}

struct cpx { float x, y; };
__device__ __forceinline__ cpx cmul(cpx a, cpx b){ return {a.x*b.x - a.y*b.y, a.x*b.y + a.y*b.x}; }
__device__ __forceinline__ cpx cadd(cpx a, cpx b){ return {a.x+b.x, a.y+b.y}; }
__device__ __forceinline__ cpx cscale(float s, cpx a){ return {s*a.x, s*a.y}; }
__device__ __forceinline__ cpx cexp_i(float t){ return {cosf(t), sinf(t)}; }
__device__ __forceinline__ cpx mulnegi(cpx z){ return {z.y, -z.x}; }   // -i*z
// runtime-condition select with STATIC indices only (v_cndmask, no scratch)
__device__ __forceinline__ cpx csel(int c, cpx a, cpx b){ return {c ? a.x : b.x, c ? a.y : b.y}; }

__device__ __forceinline__ void u3m(cpx A[2][2], float th, float ph, float de){
    float ct = cosf(0.5f*th), st = sinf(0.5f*th);
    cpx ed  = cexp_i(de);
    cpx ep  = cexp_i(ph);
    cpx epd = cexp_i(ph + de);
    A[0][0] = {ct, 0.f};
    A[0][1] = {-ed.x*st, -ed.y*st};
    A[1][0] = { ep.x*st,  ep.y*st};
    A[1][1] = { epd.x*ct, epd.y*ct};
}

// Build COLUMN c of fused gate g's 4x4 matrix. ALL array indices static;
// runtime column choice via csel (cndmask). Rule-#20 safe (round-9 fix:
// runtime-indexed locals here cost ~920KB scratch per dispatch in r6-r8).
__device__ __forceinline__ void build_gate_col(int g, int c,
                                               const float* __restrict__ conv,
                                               const float* __restrict__ pool,
                                               cpx (&Mc)[4])
{
    int l = dGL[g], pi = dGP[g];
    if (dGT[g] == 0) {
        const float* W1 = conv + l*150 + pi*15;
        const float* W2 = conv + l*150 + (pi+1)*15;
        cpx A1[2][2], B1[2][2], A2[2][2], B2[2][2];
        u3m(A1, W1[0],  W1[1],  W1[2]);
        u3m(B1, W2[3],  W2[4],  W2[5]);
        u3m(A2, W1[9],  W1[10], W1[11]);
        u3m(B2, W2[12], W2[13], W2[14]);
        const int c1 = c >> 1, c2 = c & 1;
        cpx a1r0 = csel(c1, A1[0][1], A1[0][0]);
        cpx a1r1 = csel(c1, A1[1][1], A1[1][0]);
        cpx b1r0 = csel(c2, B1[0][1], B1[0][0]);
        cpx b1r1 = csel(c2, B1[1][1], B1[1][0]);
        cpx T[4];                     // T[2*r1+r2] = A1[r1][c1] * B1[r2][c2]
        T[0] = cmul(a1r0, b1r0);
        T[1] = cmul(a1r0, b1r1);
        T[2] = cmul(a1r1, b1r0);
        T[3] = cmul(a1r1, b1r1);
        float tz = W1[6];
        cpx em = cexp_i(-0.5f*tz), ep = cexp_i(0.5f*tz);
        T[0] = cmul(em, T[0]); T[1] = cmul(ep, T[1]);
        T[2] = cmul(ep, T[2]); T[3] = cmul(em, T[3]);
        float ty = W1[7]; float cy = cosf(0.5f*ty), sy = sinf(0.5f*ty);
        cpx T2_[4];
        T2_[0] = cadd(cscale(cy,T[0]), mulnegi(cscale(-sy, T[3])));
        T2_[1] = cadd(cscale(cy,T[1]), mulnegi(cscale( sy, T[2])));
        T2_[2] = cadd(cscale(cy,T[2]), mulnegi(cscale( sy, T[1])));
        T2_[3] = cadd(cscale(cy,T[3]), mulnegi(cscale(-sy, T[0])));
        float tx = W1[8]; float cx = cosf(0.5f*tx), sx = sinf(0.5f*tx);
        cpx T3_[4];
        T3_[0] = cadd(cscale(cx,T2_[0]), mulnegi(cscale(sx, T2_[3])));
        T3_[1] = cadd(cscale(cx,T2_[1]), mulnegi(cscale(sx, T2_[2])));
        T3_[2] = cadd(cscale(cx,T2_[2]), mulnegi(cscale(sx, T2_[1])));
        T3_[3] = cadd(cscale(cx,T2_[3]), mulnegi(cscale(sx, T2_[0])));
        cpx K2[4][4];
        #pragma unroll
        for (int r1=0;r1<2;++r1)
        #pragma unroll
        for (int r2=0;r2<2;++r2)
        #pragma unroll
        for (int d1=0;d1<2;++d1)
        #pragma unroll
        for (int d2=0;d2<2;++d2)
            K2[2*r1+r2][2*d1+d2] = cmul(A2[r1][d1], B2[r2][d2]);
        #pragma unroll
        for (int r=0;r<4;++r) {
            cpx acc = {0.f, 0.f};
            #pragma unroll
            for (int m=0;m<4;++m) acc = cadd(acc, cmul(K2[r][m], T3_[m]));
            Mc[r] = acc;
        }
    } else {
        const float* Pp = pool + l*15 + pi*3;
        float phi = Pp[0], th = Pp[1], om = Pp[2];
        float ct = cosf(0.5f*th), st = sinf(0.5f*th);
        cpx z = {0.f, 0.f}, one = {1.f, 0.f};
        cpx m22 = cscale( ct, cexp_i(-0.5f*(phi+om)));
        cpx m32 = cscale( st, cexp_i(-0.5f*(phi-om)));
        cpx m23 = cscale(-st, cexp_i( 0.5f*(phi-om)));
        cpx m33 = cscale( ct, cexp_i( 0.5f*(phi+om)));
        Mc[0] = csel(c == 0, one, z);
        Mc[1] = csel(c == 1, one, z);
        Mc[2] = csel(c == 2, m22, csel(c == 3, m23, z));
        Mc[3] = csel(c == 2, m32, csel(c == 3, m33, z));
    }
}

// ---- sim helpers -----------------------------------------------------------

__device__ __forceinline__ v2f cfma(v2f m, v2f v, v2f acc) {
    v2f sw = {v.y, v.x};
    v2f my = {-m.y, m.y};
    v2f t = __builtin_elementwise_fma(my, sw, acc);
    v2f mx = {m.x, m.x};
    return __builtin_elementwise_fma(mx, v, t);
}
__device__ __forceinline__ v2f cmulv(v2f a, v2f b) { return cfma(a, b, (v2f){0.f,0.f}); }
__device__ __forceinline__ v2f vsel(int c, v2f a, v2f b) {
    return (v2f){ c ? a.x : b.x, c ? a.y : b.y };
}

// wave-local LDS fence: drain this wave's outstanding DS ops; no s_barrier.
__device__ __forceinline__ void wave_lds_fence() {
    asm volatile("s_waitcnt lgkmcnt(0)" ::: "memory");
}

// dense 4x4 gate on register bits P1,P2; matrix loaded from LDS inside.
// NO sched_barrier anywhere: the compiler may hoist these ds_reads into the
// previous gate's FMA stream (hides ~120cyc LDS latency; r6-r8 proved the
// spills never came from this hoisting).
template<int P1, int P2>
__device__ __forceinline__ void gate4(v2f (&st)[16], const float2* __restrict__ g) {
    v2f m[16];
    const float4* g4 = reinterpret_cast<const float4*>(g);
    #pragma unroll
    for (int k = 0; k < 8; ++k) {
        float4 t = g4[k];
        m[2*k]   = (v2f){t.x, t.y};
        m[2*k+1] = (v2f){t.z, t.w};
    }
    constexpr int M1 = 1 << P1, M2 = 1 << P2;
    #pragma unroll
    for (int b = 0; b < 16; ++b) {
        if (b & (M1 | M2)) continue;
        v2f v0 = st[b], v1 = st[b|M2], v2 = st[b|M1], v3 = st[b|M1|M2];
        #pragma unroll
        for (int row = 0; row < 4; ++row) {
            v2f acc = cfma(m[row*4+0], v0, (v2f){0.f, 0.f});
            acc = cfma(m[row*4+1], v1, acc);
            acc = cfma(m[row*4+2], v2, acc);
            acc = cfma(m[row*4+3], v3, acc);
            st[b | ((row>>1) ? M1 : 0) | ((row&1) ? M2 : 0)] = acc;
        }
    }
}

// CRot on register bits: P1 = ctrl, P2 = tgt. Loads active 2x2 block only.
template<int P1, int P2>
__device__ __forceinline__ void crot4(v2f (&st)[16], const float2* __restrict__ g) {
    const float4* g4 = reinterpret_cast<const float4*>(g);
    float4 a = g4[5], bb = g4[7];
    v2f m22 = {a.x,a.y}, m23 = {a.z,a.w}, m32 = {bb.x,bb.y}, m33 = {bb.z,bb.w};
    constexpr int M1 = 1 << P1, M2 = 1 << P2;
    #pragma unroll
    for (int b = 0; b < 16; ++b) {
        if (!(b & M1) || (b & M2)) continue;
        v2f v2_ = st[b], v3_ = st[b|M2];
        st[b]    = cfma(m23, v3_, cmulv(m22, v2_));
        st[b|M2] = cfma(m33, v3_, cmulv(m32, v2_));
    }
}

// Mixed CRot: ctrl bit at reg pos PCTRL, tgt bit at LANE bit LBIT.
template<int PCTRL, int LBIT>
__device__ __forceinline__ void crotx(v2f (&st)[16], const float2* __restrict__ g, int lane) {
    const float4* g4 = reinterpret_cast<const float4*>(g);
    float4 a = g4[5], bb = g4[7];
    v2f m22 = {a.x,a.y}, m23 = {a.z,a.w}, m32 = {bb.x,bb.y}, m33 = {bb.z,bb.w};
    const int beta = (lane >> LBIT) & 1;
    v2f S0 = vsel(beta, m33, m22);
    v2f S1 = vsel(beta, m32, m23);
    constexpr int M1 = 1 << PCTRL;
    #pragma unroll
    for (int b = 0; b < 16; ++b) {
        if (!(b & M1)) continue;         // ctrl = 1 amps
        v2f u = st[b], p;
        p.x = __shfl_xor(u.x, 1 << LBIT);
        p.y = __shfl_xor(u.y, 1 << LBIT);
        st[b] = cfma(S1, p, cmulv(S0, u));
    }
}

// Mixed dense gate: one bit at reg pos PREG, other at LANE bit LBIT.
template<int PREG, int LBIT>
__device__ __forceinline__ void gate4x(v2f (&st)[16], const float2* __restrict__ g, int lane) {
    v2f m[16];
    const float4* g4 = reinterpret_cast<const float4*>(g);
    #pragma unroll
    for (int k = 0; k < 8; ++k) {
        float4 t = g4[k];
        m[2*k]   = (v2f){t.x, t.y};
        m[2*k+1] = (v2f){t.z, t.w};
    }
    const int beta = (lane >> LBIT) & 1;
    v2f A00 = vsel(beta, m[5],  m[0]);
    v2f A01 = vsel(beta, m[4],  m[1]);
    v2f A02 = vsel(beta, m[7],  m[2]);
    v2f A03 = vsel(beta, m[6],  m[3]);
    v2f A10 = vsel(beta, m[13], m[8]);
    v2f A11 = vsel(beta, m[12], m[9]);
    v2f A12 = vsel(beta, m[15], m[10]);
    v2f A13 = vsel(beta, m[14], m[11]);
    constexpr int M1 = 1 << PREG;
    #pragma unroll
    for (int b = 0; b < 16; ++b) {
        if (b & M1) continue;
        v2f u0 = st[b], u1 = st[b|M1], p0, p1;
        p0.x = __shfl_xor(u0.x, 1 << LBIT); p0.y = __shfl_xor(u0.y, 1 << LBIT);
        p1.x = __shfl_xor(u1.x, 1 << LBIT); p1.y = __shfl_xor(u1.y, 1 << LBIT);
        v2f r0 = cfma(A03, p1, cfma(A02, u1, cfma(A01, p0, cmulv(A00, u0))));
        v2f r1 = cfma(A13, p1, cfma(A12, u1, cfma(A11, p0, cmulv(A10, u0))));
        st[b] = r0; st[b|M1] = r1;
    }
}

template<int PH>
__device__ __forceinline__ int base_of(int lane) {
    int b = 0;
    #pragma unroll
    for (int j = 0; j < 6; ++j) b |= ((lane >> j) & 1) << LANEB[PH][j];
    return b;
}

// LDS re-permute (double-buffered, wave-local) from phase P to phase P+1.
template<int P>
__device__ __forceinline__ void permute(v2f (&st)[16], char* buf, int lane) {
    int bw0 = base_of<P>(lane);
    int bw = (bw0 ^ hswz(P, bw0)) << 3;
    #pragma unroll
    for (int r = 0; r < 16; ++r) {
        const int o = offsL(P, r);
        const int C = (o ^ hswz(P, o)) << 3;
        *reinterpret_cast<v2f*>(buf + (bw ^ C)) = st[r];
    }
    wave_lds_fence();
    int br0 = base_of<P+1>(lane);
    int br = (br0 ^ hswz(P, br0)) << 3;
    #pragma unroll
    for (int r = 0; r < 16; ++r) {
        const int o = offsL(P+1, r);
        const int C = (o ^ hswz(P, o)) << 3;
        st[r] = *reinterpret_cast<const v2f*>(buf + (br ^ C));
    }
}

// Single fused kernel. Block = 256 threads = 4 waves = 4 samples.
__global__ __launch_bounds__(256, 2) void hqtcn_fused(
    const float* __restrict__ x,      // (16, 32, 128)
    const float* __restrict__ fc_w,   // (10, 256)
    const float* __restrict__ fc_b,   // (10,)
    const float* __restrict__ conv,   // (3, 10, 15)
    const float* __restrict__ pool,   // (3, 5, 3)
    float* __restrict__ out)          // (1936,)
{
    __shared__ float2 gmat[NGATES*16];        // 2944 B gate matrices
    __shared__ float2 pbuf[WPB][2][1024];     // 2 x 8 KB per-wave permute bufs

    const int tid  = threadIdx.x;
    const int wid  = tid >> 6;
    const int lane = tid & 63;
    const int s = blockIdx.x * WPB + wid;     // 484*4 = 1936 exact
    const int b = s / NWIN, w = s % NWIN;

    // ---- issue x loads early
    float xv[4];
    #pragma unroll
    for (int j = 0; j < 4; ++j) {
        int f = lane + 64*j;
        xv[j] = x[b*4096 + (f >> 3)*128 + w + (f & 7)];
    }

    // ---- parallel gate build: thread (g, c) computes column c of gate g
    if (tid < 4*NGATES) {
        cpx Mc[4];
        build_gate_col(tid >> 2, tid & 3, conv, pool, Mc);
        #pragma unroll
        for (int r = 0; r < 4; ++r)
            gmat[(tid>>2)*16 + r*4 + (tid&3)] = make_float2(Mc[r].x, Mc[r].y);
    }

    // ---- angles (per wave)
    float cq[NQ], sq[NQ];
    #pragma unroll
    for (int e = 0; e < NQ; ++e) {
        float v = 0.f;
        #pragma unroll
        for (int j = 0; j < 4; ++j)
            v = fmaf(xv[j], fc_w[e*256 + lane + 64*j], v);
        #pragma unroll
        for (int off = 32; off >= 1; off >>= 1) v += __shfl_xor(v, off);
        float h = 0.5f * (v + fc_b[e]);
        __sincosf(h, &sq[e], &cq[e]);
    }
    __syncthreads();    // the only block-wide barrier (gmat ready)

    // ---- init: apply g0..g4 analytically. W[p] = G_p @ [cc',cs',sc',ss']
    v2f W[5][4];
    #pragma unroll
    for (int p = 0; p < 5; ++p) {
        float ca = cq[2*p], sa = sq[2*p], cb = cq[2*p+1], sb = sq[2*p+1];
        float u0 = ca*cb, u1 = ca*sb, u2 = sa*cb, u3_ = sa*sb;
        const float2* G = gmat + p*16;
        #pragma unroll
        for (int i = 0; i < 4; ++i) {
            float2 g0 = G[i*4+0], g1 = G[i*4+1], g2 = G[i*4+2], g3 = G[i*4+3];
            v2f acc = (v2f){g0.x*u0, g0.y*u0};
            acc = __builtin_elementwise_fma((v2f){u1,u1}, (v2f){g1.x,g1.y}, acc);
            acc = __builtin_elementwise_fma((v2f){u2,u2}, (v2f){g2.x,g2.y}, acc);
            acc = __builtin_elementwise_fma((v2f){u3_,u3_}, (v2f){g3.x,g3.y}, acc);
            W[p][i] = acc;
        }
    }
    // Phase-A mapping: reg bits = logical {5,6,7,8}; lane bits = {0,1,2,3,4,9}
    const int l0 = lane&1, l1=(lane>>1)&1, l2=(lane>>2)&1,
              l3=(lane>>3)&1, l4=(lane>>4)&1, l5=(lane>>5)&1;
    v2f W3k = vsel(l3, vsel(l2, W[3][3], W[3][2]), vsel(l2, W[3][1], W[3][0]));
    v2f W4k = vsel(l1, vsel(l0, W[4][3], W[4][2]), vsel(l0, W[4][1], W[4][0]));
    v2f UL  = cmulv(W3k, W4k);
    v2f W2lo = vsel(l4, W[2][1], W[2][0]);
    v2f W2hi = vsel(l4, W[2][3], W[2][2]);
    v2f P0v = cmulv(UL, vsel(l5, W[0][2], W[0][0]));
    v2f P1v = cmulv(UL, vsel(l5, W[0][3], W[0][1]));
    v2f PW[2][4];
    #pragma unroll
    for (int j = 0; j < 4; ++j) {
        PW[0][j] = cmulv(P0v, W[1][j]);
        PW[1][j] = cmulv(P1v, W[1][j]);
    }
    v2f st[16];
    #pragma unroll
    for (int r = 0; r < 16; ++r)
        st[r] = cmulv(PW[(r>>3)&1][(r>>1)&3], (r&1) ? W2hi : W2lo);

    const float2* gm = gmat;

    // Phase A: reg {5,6,7,8}, lane {0,1,2,3,4,9}
    gate4<3,2>(st, gm + 5*16);          // g5  {8,7}
    gate4<1,0>(st, gm + 6*16);          // g6  {6,5}
    crot4<1,2>(st, gm + 10*16);         // g10 ctrl6->7
    crotx<3,5>(st, gm + 9*16, lane);    // g9  ctrl8(reg3)->9(lane5)
    permute<0>(st, (char*)&pbuf[wid][0][0], lane);
    // Phase B: reg {1,2,3,4}, lane {0,5,6,7,8,9}
    gate4<3,2>(st, gm + 7*16);          // g7  {4,3}
    gate4<1,0>(st, gm + 8*16);          // g8  {2,1}
    crot4<1,2>(st, gm + 12*16);         // g12 ctrl2->3
    crotx<3,1>(st, gm + 11*16, lane);   // g11 ctrl4(reg3)->5(lane1)
    permute<1>(st, (char*)&pbuf[wid][1][0], lane);
    // Phase D: reg {0,1,3,5}, lane {2,4,6,7,8,9}
    crot4<0,1>(st, gm + 13*16);         // g13 ctrl0->1
    gate4<3,2>(st, gm + 15*16);         // g15 {5,3}
    gate4<2,1>(st, gm + 17*16);         // g17 {3,1}
    permute<2>(st, (char*)&pbuf[wid][0][0], lane);
    // Phase E: reg {3,5,7,9}, lane {0,1,2,4,6,8}
    gate4<3,2>(st, gm + 14*16);         // g14 {9,7}
    gate4<2,1>(st, gm + 16*16);         // g16 {7,5}
    crot4<2,3>(st, gm + 18*16);         // g18 ctrl7->9
    crot4<0,1>(st, gm + 19*16);         // g19 ctrl3->5
    gate4<3,1>(st, gm + 20*16);         // g20 {9,5}
    gate4x<1,1>(st, gm + 21*16, lane);  // g21 {5(reg1), 1(lane1)}
    crot4<1,3>(st, gm + 22*16);         // g22 ctrl5->9

    // ---- <Z0>: logical bit 9 at reg pos 3 in phase E.
    float accp = 0.f, accm = 0.f;
    #pragma unroll
    for (int r = 0; r < 16; ++r) {
        v2f a = st[r];
        float p2 = fmaf(a.x, a.x, a.y*a.y);
        if ((r >> 3) & 1) accm += p2; else accp += p2;
    }
    float acc = accp - accm;
    #pragma unroll
    for (int off = 32; off >= 1; off >>= 1) acc += __shfl_xor(acc, off);
    if (lane == 0) out[s] = acc;
}

extern "C" void kernel_launch(void* const* d_in, const int* in_sizes, int n_in,
                              void* d_out, int out_size, void* d_ws, size_t ws_size,
                              hipStream_t stream) {
    const float* x     = (const float*)d_in[0];
    const float* fc_w  = (const float*)d_in[1];
    const float* fc_b  = (const float*)d_in[2];
    const float* convp = (const float*)d_in[3];
    const float* poolp = (const float*)d_in[4];
    float* out = (float*)d_out;

    hqtcn_fused<<<(16*NWIN)/WPB, 64*WPB, 0, stream>>>(x, fc_w, fc_b, convp, poolp, out);
}